// Round 6
// baseline (63.975 us; speedup 1.0000x reference)
//
#include <hip/hip_runtime.h>
#include <hip/hip_bf16.h>

// Problem constants
#define TT   1024            // time steps
#define DD   1280            // feature dim
#define WW   320             // DD / POOL
#define CC   20              // channels
#define HALF 10
#define TW   (TT*WW)         // 327680
#define LIN  (CC*WW)         // 6400  (GEMM K)
#define OUTD 80              // GEMM N
#define NSPLIT 20
#define KCHUNK (LIN/NSPLIT)  // 320
#define KSTEPS (KCHUNK/32)   // 10
#define LOG2E 1.4426950408889634f
#define XPAD 384             // floats of guard on each side of x

#define POOL_BLOCKS (TW/256)             // 1280
#define CVT_BLOCKS  ((OUTD*LIN)/(256*8)) // 250

typedef __attribute__((ext_vector_type(4))) float f32x4;
typedef __attribute__((ext_vector_type(8))) short bf16x8;

// RNE float->bf16, finite values only (no NaN path)
__device__ __forceinline__ ushort f2bf(float v) {
    unsigned u = __float_as_uint(v);
    u += 0x7FFFu + ((u >> 16) & 1u);
    return (ushort)(u >> 16);
}

// pack two f32 -> two bf16 in one instruction
__device__ __forceinline__ unsigned pk_bf16(float lo, float hi) {
    unsigned r;
    asm("v_cvt_pk_bf16_f32 %0, %1, %2" : "=v"(r) : "v"(lo), "v"(hi));
    return r;
}

// ---------------- Kernel 1: MaxPool2d((1,4))  +  dense_w fp32->bf16 ----------------
__global__ __launch_bounds__(256) void k_prep(const float* __restrict__ f,
                                              float* __restrict__ x,
                                              const float* __restrict__ dw,
                                              ushort* __restrict__ dwb) {
    int b = blockIdx.x;
    if (b < POOL_BLOCKS) {
        int idx = b * 256 + threadIdx.x;               // over TW, exact
        float4 v = reinterpret_cast<const float4*>(f)[idx];
        x[idx] = fmaxf(fmaxf(v.x, v.y), fmaxf(v.z, v.w));
    } else {
        int i = ((b - POOL_BLOCKS) * 256 + threadIdx.x) * 8;
        float4 a = reinterpret_cast<const float4*>(dw + i)[0];
        float4 c = reinterpret_cast<const float4*>(dw + i)[1];
        reinterpret_cast<ushort4*>(dwb + i)[0] =
            make_ushort4(f2bf(a.x), f2bf(a.y), f2bf(a.z), f2bf(a.w));
        reinterpret_cast<ushort4*>(dwb + i)[1] =
            make_ushort4(f2bf(c.x), f2bf(c.y), f2bf(c.z), f2bf(c.w));
    }
}

// ---------------- attention math for 2 channels, ish known at compile time ----------------
template<bool ISH>
__device__ __forceinline__ void attn2(const float xr[3][6],
                                      const float* qk, const float* B0,
                                      const float* B1, const float* B2,
                                      const float* vv, uint2* res) {
    #pragma unroll
    for (int cc = 0; cc < 2; ++cc) {
        float o[4];
        #pragma unroll
        for (int p = 0; p < 4; ++p) {
            float xc = xr[1][p + 1];
            float a  = qk[cc] * xc;
            float b0 = B0[cc] * xc, b1 = B1[cc] * xc, b2 = B2[cc] * xc;
            float s[9];
            #pragma unroll
            for (int dt = 0; dt < 3; ++dt) {
                float bdt = (dt == 0) ? b0 : ((dt == 1) ? b1 : b2);
                #pragma unroll
                for (int dw = 0; dw < 3; ++dw) {
                    float bias = ISH ? bdt : ((dw == 0) ? b0 : ((dw == 1) ? b1 : b2));
                    s[dt * 3 + dw] = fmaf(a, xr[dt][p + dw], bias);
                }
            }
            // max3-shaped tree: 4 instructions
            float m012 = fmaxf(fmaxf(s[0], s[1]), s[2]);
            float m345 = fmaxf(fmaxf(s[3], s[4]), s[5]);
            float m678 = fmaxf(fmaxf(s[6], s[7]), s[8]);
            float m    = fmaxf(fmaxf(m012, m345), m678);
            // two-accumulator sums for ILP
            float den0 = 0.f, den1 = 0.f, num0 = 0.f, num1 = 0.f;
            #pragma unroll
            for (int i = 0; i < 9; ++i) {
                float e = __builtin_amdgcn_exp2f(s[i] - m);
                if (i & 1) { den1 += e; num1 = fmaf(e, xr[i / 3][p + i % 3], num1); }
                else       { den0 += e; num0 = fmaf(e, xr[i / 3][p + i % 3], num0); }
            }
            float den = den0 + den1, num = num0 + num1;
            o[p] = fmaxf(vv[cc] * (num * __builtin_amdgcn_rcpf(den)), 0.0f);
        }
        res[cc] = make_uint2(pk_bf16(o[0], o[1]), pk_bf16(o[2], o[3]));
    }
}

// ---------------- Kernel 2: 3x3 windowed attention -> bf16 ----------------
// grid (TW/4/256, 10): blockIdx.y = group of 2 channels; thread = 4 w-positions.
__global__ __launch_bounds__(256, 8) void k_attn(const float* __restrict__ x,
                                                 const float* __restrict__ wq,
                                                 const float* __restrict__ wk,
                                                 const float* __restrict__ wv,
                                                 const float* __restrict__ rh,
                                                 const float* __restrict__ rw,
                                                 ushort* __restrict__ att) {
    int idx = blockIdx.x * 256 + threadIdx.x;          // 0..81919
    int t  = idx / (WW / 4);
    int g  = idx % (WW / 4);
    int w0 = g * 4;
    int c0 = blockIdx.y * 2;                           // block-uniform channel pair

    // per-channel coefficients (uniform loads; products computed once)
    float qk[2], B0[2], B1[2], B2[2], vv2[2];
    #pragma unroll
    for (int cc = 0; cc < 2; ++cc) {
        int c = c0 + cc;
        float wqc = wq[c];
        qk[cc]  = wqc * wk[c] * LOG2E;
        vv2[cc] = wv[c];
        const float* rp = (c < HALF) ? (rh + c * 3) : (rw + (c - HALF) * 3);
        B0[cc] = wqc * rp[0] * LOG2E;
        B1[cc] = wqc * rp[1] * LOG2E;
        B2[cc] = wqc * rp[2] * LOG2E;
    }

    // x[t-1..t+1][w0-1..w0+4] via 2x float4 + 1 scalar per row (guard pads keep OOB mapped)
    float xr[3][6];
    const float* xb = x + t * WW + w0;
    #pragma unroll
    for (int dt = 0; dt < 3; ++dt) {
        const float* rp = xb + (dt - 1) * WW;
        float4 va = *reinterpret_cast<const float4*>(rp - 4);
        float4 vb = *reinterpret_cast<const float4*>(rp);
        float  vc = rp[4];
        int tt2 = t + dt - 1;
        bool rok = (tt2 >= 0) & (tt2 < TT);
        xr[dt][0] = (rok & (g > 0))  ? va.w : 0.f;
        xr[dt][1] = rok ? vb.x : 0.f;
        xr[dt][2] = rok ? vb.y : 0.f;
        xr[dt][3] = rok ? vb.z : 0.f;
        xr[dt][4] = rok ? vb.w : 0.f;
        xr[dt][5] = (rok & (g < 79)) ? vc : 0.f;
    }

    uint2 res[2];
    if (c0 < HALF) attn2<true >(xr, qk, B0, B1, B2, vv2, res);
    else           attn2<false>(xr, qk, B0, B1, B2, vv2, res);

    #pragma unroll
    for (int cc = 0; cc < 2; ++cc)
        *reinterpret_cast<uint2*>(att + (size_t)(c0 + cc) * TW + t * WW + w0) = res[cc];
}

// ---------------- Kernel 3: bf16 MFMA split-K GEMM  [1024 x 6400] * [6400 x 80]^T ----------------
// one wave per block: 16 rows x 80 cols, KCHUNK of K
__global__ __launch_bounds__(64) void k_gemm(const ushort* __restrict__ A,
                                             const ushort* __restrict__ B,
                                             float* __restrict__ part) {
    int lane = threadIdx.x;
    int mt = blockIdx.x;        // 0..63  (M tile of 16 rows)
    int sp = blockIdx.y;        // 0..NSPLIT-1
    int r16 = lane & 15;        // A row / B col / C col
    int kg  = lane >> 4;        // k-group 0..3

    const ushort* ap = A + (size_t)(mt * 16 + r16) * LIN + sp * KCHUNK + kg * 8;
    const ushort* bp = B + (size_t)r16 * LIN + sp * KCHUNK + kg * 8;

    f32x4 acc[5] = {};
    for (int ks = 0; ks < KSTEPS; ++ks) {
        bf16x8 af = *reinterpret_cast<const bf16x8*>(ap);
        #pragma unroll
        for (int j = 0; j < 5; ++j) {
            bf16x8 bfr = *reinterpret_cast<const bf16x8*>(bp + (size_t)j * 16 * LIN);
            acc[j] = __builtin_amdgcn_mfma_f32_16x16x32_bf16(af, bfr, acc[j], 0, 0, 0);
        }
        ap += 32;
        bp += 32;
    }

    // C/D layout: col = lane&15, row = (lane>>4)*4 + reg
    float* p = part + (size_t)sp * TT * OUTD + (size_t)(mt * 16 + kg * 4) * OUTD + r16;
    #pragma unroll
    for (int j = 0; j < 5; ++j)
        #pragma unroll
        for (int r = 0; r < 4; ++r)
            p[(size_t)r * OUTD + j * 16] = acc[j][r];
}

// ---------------- Kernel 4: split-K reduce + bias ----------------
__global__ __launch_bounds__(256) void k_reduce(const float* __restrict__ part,
                                                const float* __restrict__ bias,
                                                float* __restrict__ out) {
    int idx = blockIdx.x * 256 + threadIdx.x;   // over TT*OUTD = 81920, exact
    int o = idx % OUTD;
    float s = bias[o];
    #pragma unroll
    for (int sp = 0; sp < NSPLIT; ++sp) s += part[(size_t)sp * TT * OUTD + idx];
    out[idx] = s;
}

extern "C" void kernel_launch(void* const* d_in, const int* in_sizes, int n_in,
                              void* d_out, int out_size, void* d_ws, size_t ws_size,
                              hipStream_t stream) {
    const float* feature = (const float*)d_in[0];
    const float* wq      = (const float*)d_in[1];
    const float* wk      = (const float*)d_in[2];
    const float* wv      = (const float*)d_in[3];
    const float* rel_h   = (const float*)d_in[4];
    const float* rel_w   = (const float*)d_in[5];
    const float* dense_w = (const float*)d_in[6];
    const float* dense_b = (const float*)d_in[7];
    float* out = (float*)d_out;

    float*  ws   = (float*)d_ws;
    float*  x    = ws + XPAD;                            // TW floats, guarded both sides
    ushort* att  = (ushort*)(ws + 2 * XPAD + TW);        // CC*TW bf16         (13.1 MB)
    ushort* dwb  = att + (size_t)CC * TW;                // OUTD*LIN bf16      (1.02 MB)
    float*  part = (float*)(dwb + (size_t)OUTD * LIN);   // NSPLIT*TT*OUTD f32 (6.55 MB)

    k_prep  <<<POOL_BLOCKS + CVT_BLOCKS, 256, 0, stream>>>(feature, x, dense_w, dwb);
    k_attn  <<<dim3(TW/4/256, 10), 256, 0, stream>>>(x, wq, wk, wv, rel_h, rel_w, att);
    k_gemm  <<<dim3(TT/16, NSPLIT), 64, 0, stream>>>(att, dwb, part);
    k_reduce<<<(TT*OUTD)/256, 256, 0, stream>>>(part, dense_b, out);
}

// Round 8
// 33.113 us; speedup vs baseline: 1.9320x; 1.9320x over previous
//
#include <hip/hip_runtime.h>
#include <hip/hip_bf16.h>

// Problem constants
#define TT   1024            // time steps
#define DD   1280            // feature dim
#define WW   320             // DD / POOL
#define CC   20              // channels
#define HALF 10
#define TW   (TT*WW)         // 327680
#define LIN  (CC*WW)         // 6400  (GEMM K)
#define OUTD 80              // GEMM N
#define NSPLIT 20            // split-K: 320 cols each
#define LOG2E 1.4426950408889634f
#define XPAD 384             // floats of guard on each side of x

#define POOL_BLOCKS (TW/256)             // 1280
#define CVT_BLOCKS  ((OUTD*LIN)/(256*8)) // 250

typedef __attribute__((ext_vector_type(4))) float f32x4;
typedef __attribute__((ext_vector_type(8))) short bf16x8;

// RNE float->bf16, finite values only (no NaN path)
__device__ __forceinline__ ushort f2bf(float v) {
    unsigned u = __float_as_uint(v);
    u += 0x7FFFu + ((u >> 16) & 1u);
    return (ushort)(u >> 16);
}

// pack two f32 -> two bf16 in one instruction
__device__ __forceinline__ unsigned pk_bf16(float lo, float hi) {
    unsigned r;
    asm("v_cvt_pk_bf16_f32 %0, %1, %2" : "=v"(r) : "v"(lo), "v"(hi));
    return r;
}

// ---------------- Kernel 1: MaxPool2d((1,4))  +  dense_w fp32->bf16 ----------------
__global__ __launch_bounds__(256) void k_prep(const float* __restrict__ f,
                                              float* __restrict__ x,
                                              const float* __restrict__ dw,
                                              ushort* __restrict__ dwb) {
    int b = blockIdx.x;
    if (b < POOL_BLOCKS) {
        int idx = b * 256 + threadIdx.x;               // over TW, exact
        float4 v = reinterpret_cast<const float4*>(f)[idx];
        x[idx] = fmaxf(fmaxf(v.x, v.y), fmaxf(v.z, v.w));
    } else {
        int i = ((b - POOL_BLOCKS) * 256 + threadIdx.x) * 8;
        float4 a = reinterpret_cast<const float4*>(dw + i)[0];
        float4 c = reinterpret_cast<const float4*>(dw + i)[1];
        reinterpret_cast<ushort4*>(dwb + i)[0] =
            make_ushort4(f2bf(a.x), f2bf(a.y), f2bf(a.z), f2bf(a.w));
        reinterpret_cast<ushort4*>(dwb + i)[1] =
            make_ushort4(f2bf(c.x), f2bf(c.y), f2bf(c.z), f2bf(c.w));
    }
}

// ---------------- Kernel 2: FUSED attention + split-K MFMA GEMM ----------------
// Flatten semantics: GEMM A-row r, col k  =  att linear element r*6400 + k,
// i.e. with k = sp*320 + w:  c*1024 + t = r*20 + sp.
// Block (mt, sp): 16 A-rows (r = mt*16+j), K-chunk cols [sp*320, sp*320+320).
// Phase 1: 16 att rows (c_j, t_j), ct_j = (mt*16+j)*20+sp, all 320 w -> LDS bf16.
// Phase 2: 4 waves MFMA 16x80 over 10 K-steps (3/3/2/2), LDS reduce, write partial.
__global__ __launch_bounds__(256, 5) void k_fused(const float* __restrict__ x,
                                                  const float* __restrict__ wq,
                                                  const float* __restrict__ wk,
                                                  const float* __restrict__ wv,
                                                  const float* __restrict__ rh,
                                                  const float* __restrict__ rw,
                                                  const ushort* __restrict__ dwb,
                                                  float* __restrict__ part) {
    __shared__ __align__(16) ushort alds[16][328];     // [row][w] bf16, +8 pad
    __shared__ float red[16][81];                      // cross-wave f32 reduce

    int tid = threadIdx.x;
    int mt  = blockIdx.x;          // 0..63  A-row tile
    int sp  = blockIdx.y;          // 0..19  K-chunk

    // ---- Phase 1: attention, one channel per thread-row ----
    {
        int j  = tid >> 4;                 // local A-row 0..15
        int wg = tid & 15;                 // w-group 0..15 (handles 5 strided groups)
        int ct = (mt * 16 + j) * 20 + sp;  // c*1024 + t
        int t  = ct & 1023;
        int c  = ct >> 10;
        bool ish = (c < HALF);

        float wqc = wq[c];
        float qk  = wqc * wk[c] * LOG2E;
        float vv  = wv[c];
        const float* rp = ish ? (rh + c * 3) : (rw + (c - HALF) * 3);
        float r0 = wqc * rp[0] * LOG2E;
        float r1 = wqc * rp[1] * LOG2E;
        float r2 = wqc * rp[2] * LOG2E;
        // bias coefficient per window slot: ish -> varies with dt, else with dw
        float Bco[9];
        #pragma unroll
        for (int i = 0; i < 9; ++i) {
            float bh = (i < 3) ? r0 : ((i < 6) ? r1 : r2);
            float bw = ((i % 3) == 0) ? r0 : (((i % 3) == 1) ? r1 : r2);
            Bco[i] = ish ? bh : bw;
        }

        bool rok0 = (t > 0), rok2 = (t < TT - 1);
        const float* xb0 = x + t * WW;

        for (int u = 0; u < 5; ++u) {
            int gg = wg + 16 * u;          // global w-group 0..79
            int w0 = gg * 4;
            float xr[3][6];
            #pragma unroll
            for (int dt = 0; dt < 3; ++dt) {
                const float* rpx = xb0 + (dt - 1) * WW + w0;
                float4 va = *reinterpret_cast<const float4*>(rpx - 4);
                float4 vb = *reinterpret_cast<const float4*>(rpx);
                float  vc = rpx[4];
                bool rok = (dt == 1) ? true : ((dt == 0) ? rok0 : rok2);
                xr[dt][0] = (rok & (gg > 0))  ? va.w : 0.f;
                xr[dt][1] = rok ? vb.x : 0.f;
                xr[dt][2] = rok ? vb.y : 0.f;
                xr[dt][3] = rok ? vb.z : 0.f;
                xr[dt][4] = rok ? vb.w : 0.f;
                xr[dt][5] = (rok & (gg < 79)) ? vc : 0.f;
            }

            float o[4];
            #pragma unroll
            for (int p = 0; p < 4; ++p) {
                float xc = xr[1][p + 1];
                float a  = qk * xc;
                float s[9];
                #pragma unroll
                for (int i = 0; i < 9; ++i)
                    s[i] = fmaf(a, xr[i / 3][p + i % 3], Bco[i] * xc);
                float m012 = fmaxf(fmaxf(s[0], s[1]), s[2]);
                float m345 = fmaxf(fmaxf(s[3], s[4]), s[5]);
                float m678 = fmaxf(fmaxf(s[6], s[7]), s[8]);
                float m    = fmaxf(fmaxf(m012, m345), m678);
                float den0 = 0.f, den1 = 0.f, num0 = 0.f, num1 = 0.f;
                #pragma unroll
                for (int i = 0; i < 9; ++i) {
                    float e = __builtin_amdgcn_exp2f(s[i] - m);
                    if (i & 1) { den1 += e; num1 = fmaf(e, xr[i / 3][p + i % 3], num1); }
                    else       { den0 += e; num0 = fmaf(e, xr[i / 3][p + i % 3], num0); }
                }
                float den = den0 + den1, num = num0 + num1;
                o[p] = fmaxf(vv * (num * __builtin_amdgcn_rcpf(den)), 0.0f);
            }
            *reinterpret_cast<uint2*>(&alds[j][w0]) =
                make_uint2(pk_bf16(o[0], o[1]), pk_bf16(o[2], o[3]));
        }
    }

    __syncthreads();

    // ---- Phase 2: MFMA 16x80 over the 320-col K-chunk ----
    int wave = tid >> 6;
    int lane = tid & 63;
    int r16  = lane & 15;          // A row / B out-col
    int kg   = lane >> 4;          // k-group 0..3

    int ks0 = (wave < 2) ? wave * 3 : 6 + (wave - 2) * 2;
    int ksn = (wave < 2) ? 3 : 2;

    const ushort* bp = dwb + (size_t)r16 * LIN + sp * 320 + kg * 8;

    f32x4 acc[5] = {};
    for (int ks = ks0; ks < ks0 + ksn; ++ks) {
        bf16x8 af = *reinterpret_cast<const bf16x8*>(&alds[r16][ks * 32 + kg * 8]);
        #pragma unroll
        for (int jj = 0; jj < 5; ++jj) {
            bf16x8 bfr = *reinterpret_cast<const bf16x8*>(bp + ks * 32 + (size_t)jj * 16 * LIN);
            acc[jj] = __builtin_amdgcn_mfma_f32_16x16x32_bf16(af, bfr, acc[jj], 0, 0, 0);
        }
    }

    // ---- cross-wave reduce in LDS (C/D: col = lane&15, row = kg*4 + reg) ----
    for (int v = 0; v < 4; ++v) {
        __syncthreads();
        if (wave == v) {
            #pragma unroll
            for (int jj = 0; jj < 5; ++jj)
                #pragma unroll
                for (int r = 0; r < 4; ++r) {
                    int row = kg * 4 + r, col = jj * 16 + r16;
                    if (v == 0) red[row][col]  = acc[jj][r];
                    else        red[row][col] += acc[jj][r];
                }
        }
    }
    __syncthreads();

    float* pp = part + (size_t)sp * TT * OUTD + (size_t)(mt * 16) * OUTD;
    for (int i2 = tid; i2 < 16 * 80; i2 += 256)
        pp[i2] = red[i2 / 80][i2 % 80];
}

// ---------------- Kernel 3: split-K reduce + bias ----------------
__global__ __launch_bounds__(256) void k_reduce(const float* __restrict__ part,
                                                const float* __restrict__ bias,
                                                float* __restrict__ out) {
    int idx = blockIdx.x * 256 + threadIdx.x;   // over TT*OUTD = 81920, exact
    int o = idx % OUTD;
    float s = bias[o];
    #pragma unroll
    for (int sp = 0; sp < NSPLIT; ++sp) s += part[(size_t)sp * TT * OUTD + idx];
    out[idx] = s;
}

extern "C" void kernel_launch(void* const* d_in, const int* in_sizes, int n_in,
                              void* d_out, int out_size, void* d_ws, size_t ws_size,
                              hipStream_t stream) {
    const float* feature = (const float*)d_in[0];
    const float* wq      = (const float*)d_in[1];
    const float* wk      = (const float*)d_in[2];
    const float* wv      = (const float*)d_in[3];
    const float* rel_h   = (const float*)d_in[4];
    const float* rel_w   = (const float*)d_in[5];
    const float* dense_w = (const float*)d_in[6];
    const float* dense_b = (const float*)d_in[7];
    float* out = (float*)d_out;

    float*  ws   = (float*)d_ws;
    float*  x    = ws + XPAD;                            // TW floats, guarded both sides
    ushort* dwb  = (ushort*)(ws + 2 * XPAD + TW);        // OUTD*LIN bf16      (1.02 MB)
    float*  part = (float*)(dwb + (size_t)OUTD * LIN);   // NSPLIT*TT*OUTD f32 (6.55 MB)

    k_prep  <<<POOL_BLOCKS + CVT_BLOCKS, 256, 0, stream>>>(feature, x, dense_w, dwb);
    k_fused <<<dim3(TT/16, NSPLIT), 256, 0, stream>>>(x, wq, wk, wv, rel_h, rel_w, dwb, part);
    k_reduce<<<(TT*OUTD)/256, 256, 0, stream>>>(part, dense_b, out);
}